// Round 5
// baseline (252.912 us; speedup 1.0000x reference)
//
#include <hip/hip_runtime.h>
#include <math.h>

// HashEncoder, round 10.
// Capacity-binning counting sort (512 spatial bins, fixed CAP slots/bin):
//   memset(cursor) -> scatter_cap (LDS-reordered) -> encode_cap_lds.
// Round-10 changes (both kernels latency-bound, total traffic ~250 MB):
//   * scatter: PTS_PER_BLK 4096->2048 (LDS 78->43 KB, 2->3 blocks/CU,
//     16->24 waves/CU); positions loaded as coalesced float4 into LDS
//     (3 dwordx4/thread instead of 12 dwords); shfl-based 2-barrier scan
//     replaces the 18-barrier ladder.
//   * encode: level-0's 8 global gathers issued BEFORE __syncthreads
//     (addresses from the prefetched record, coords clamped so garbage
//     lanes stay in-bounds) -> they complete under the barrier's vmcnt
//     drain, removing L2 latency from the post-barrier serial chain.
// Fallbacks: exact-sort pipeline, then direct kernel, if ws_size too small.

#define NBINS        512            // 8^3 spatial bins
#define BIN_SCALE    (8.0f / 0.9f)
#define SCAT_THREADS 512
#define PTS_PER_BLK  2048           // points per scatter block (512 thr x 4)
#define SCAT_ITERS   (PTS_PER_BLK / SCAT_THREADS)
#define CAP          4608           // slots per bin = mean 4096 + 8 sigma

#define ENC_THREADS  512
#define ENC_BPB      (CAP / ENC_THREADS)   // 9 blocks per bin

// Per-level LDS window dims: D = ceil(0.1125*scale) + 2
#define D1 7
#define D2 9
#define D3 11
#define A1 0
#define A2 (A1 + D1*D1*D1)          // 343
#define A3 (A2 + D2*D2*D2)          // 1072
#define LDS_TOT (A3 + D3*D3*D3)     // 2403 float4 = 38448 B -> 4 blocks/CU

typedef float vfloat4 __attribute__((ext_vector_type(4)));

__device__ __forceinline__ int bin_of(float x, float y, float z) {
    int bx = (int)(x * BIN_SCALE); bx = bx < 0 ? 0 : (bx > 7 ? 7 : bx);
    int by = (int)(y * BIN_SCALE); by = by < 0 ? 0 : (by > 7 ? 7 : by);
    int bz = (int)(z * BIN_SCALE); bz = bz < 0 ? 0 : (bz > 7 ? 7 : bz);
    return bx | (by << 3) | (bz << 6);
}

// ---------------- capacity-binning path ----------------

// cursor holds RELATIVE per-bin counts when bin_stride=CAP (cap path,
// cursor pre-zeroed), or ABSOLUTE scan offsets when bin_stride=0 (fallback).
// Records are bin-sorted in LDS first so global writes are contiguous
// per-bin runs instead of random 16 B scatter.
__global__ __launch_bounds__(SCAT_THREADS) void scatter_cap_kernel(
    const float* __restrict__ pos, int n, int* __restrict__ cursor,
    float4* __restrict__ sorted, int bin_stride)
{
    __shared__ float4         lds_rec[PTS_PER_BLK];   // 32 KB (pos staging, then records)
    __shared__ unsigned short lds_bin[PTS_PER_BLK];   // 4 KB
    __shared__ int lds_hist[NBINS];                   // 2 KB
    __shared__ int lds_lbase[NBINS];                  // 2 KB
    __shared__ int lds_gbase[NBINS];                  // 2 KB
    __shared__ int lds_wsum[8];
    // total ~43 KB -> 3 blocks/CU (24 waves/CU)

    int tid = threadIdx.x;
    long base = (long)blockIdx.x * PTS_PER_BLK;
    lds_hist[tid] = 0;

    long rem = (long)n - base;
    int tot = rem >= PTS_PER_BLK ? PTS_PER_BLK : (rem > 0 ? (int)rem : 0);

    // Phase 0: coalesced float4 load of this block's positions into LDS.
    // base*3 is divisible by 4 (base = blk*2048), so the float4 view aligns.
    float* fbuf = (float*)lds_rec;                   // capacity 8192 floats, need <=6144
    int nflt = 3 * tot;
    int nf4  = nflt >> 2;
    const float4* posv = (const float4*)(pos + base * 3);
    for (int f = tid; f < nf4; f += SCAT_THREADS)
        ((float4*)fbuf)[f] = posv[f];
    for (int q = (nf4 << 2) + tid; q < nflt; q += SCAT_THREADS)   // <=3 tail floats
        fbuf[q] = pos[base * 3 + q];
    __syncthreads();

    // Phase 1: bin + per-block rank (LDS atomics), positions kept in regs.
    float px[SCAT_ITERS], py[SCAT_ITERS], pz[SCAT_ITERS];
    int br[SCAT_ITERS];   // packed (rank<<9)|bin, or -1
#pragma unroll
    for (int j = 0; j < SCAT_ITERS; ++j) {
        int lp = j * SCAT_THREADS + tid;
        int packed = -1;
        if (lp < tot) {
            float x = fbuf[3 * lp], y = fbuf[3 * lp + 1], z = fbuf[3 * lp + 2];
            px[j] = x; py[j] = y; pz[j] = z;
            int b = bin_of(x, y, z);
            int r = atomicAdd(&lds_hist[b], 1);
            packed = (r << 9) | b;     // rank < 2048 -> fits
        }
        br[j] = packed;
    }
    __syncthreads();

    // Phase 2: block-wide exclusive scan via shfl (2 barriers total),
    // plus global base via one atomic per non-empty bin.
    int lane = tid & 63, wid = tid >> 6;
    int cntb = lds_hist[tid];
    int v = cntb;
#pragma unroll
    for (int off = 1; off < 64; off <<= 1) {
        int u = __shfl_up(v, off, 64);
        if (lane >= off) v += u;
    }
    if (lane == 63) lds_wsum[wid] = v;
    __syncthreads();
    if (tid < 8) {
        int w = lds_wsum[tid];
#pragma unroll
        for (int off = 1; off < 8; off <<= 1) {
            int u = __shfl_up(w, off, 8);
            if (tid >= off) w += u;
        }
        lds_wsum[tid] = w;             // inclusive wave sums
    }
    if (cntb) lds_gbase[tid] = atomicAdd(&cursor[tid], cntb);
    __syncthreads();
    int wbase = wid ? lds_wsum[wid - 1] : 0;
    int excl  = wbase + v - cntb;
    lds_lbase[tid] = excl;
    __syncthreads();

    // Phase 3: place records bin-sorted in LDS (overwrites fbuf; ordered
    // by the scan barriers).
#pragma unroll
    for (int j = 0; j < SCAT_ITERS; ++j) {
        if (br[j] < 0) continue;
        int b = br[j] & (NBINS - 1);
        int r = br[j] >> 9;
        int s = lds_lbase[b] + r;
        int lp = j * SCAT_THREADS + tid;
        lds_rec[s] = make_float4(px[j], py[j], pz[j], __int_as_float((int)(base + lp)));
        lds_bin[s] = (unsigned short)b;
    }
    __syncthreads();

    // Phase 4: stream LDS linearly -> contiguous per-bin runs to global.
    for (int s = tid; s < tot; s += SCAT_THREADS) {
        float4 rec = lds_rec[s];
        int b = lds_bin[s];
        int off_in_bin = s - lds_lbase[b];
        long slot = (long)b * bin_stride + lds_gbase[b] + off_in_bin;
        sorted[slot] = rec;
    }
}

// Stage one level's table window into LDS (coalesced along x).
template<int D>
__device__ __forceinline__ void stage_win(
    float4* __restrict__ dst, const float4* __restrict__ tab,
    int off, int res, int Bx, int By, int Bz, int tid)
{
    const int DD = D * D, DDD = D * D * D;
    for (int e = tid; e < DDD; e += ENC_THREADS) {
        int iz  = e / DD;
        int rem = e - iz * DD;
        int iy  = rem / D;
        int ix  = rem - iy * D;
        int gx = Bx + ix; gx = gx < 0 ? 0 : (gx > res - 1 ? res - 1 : gx);
        int gy = By + iy; gy = gy < 0 ? 0 : (gy > res - 1 ? res - 1 : gy);
        int gz = Bz + iz; gz = gz < 0 ? 0 : (gz > res - 1 ? res - 1 : gz);
        dst[e] = tab[off + gx + gy * res + gz * res * res];
    }
}

// Trilinear interp for one level, from LDS window when in range,
// exact global fallback otherwise (rare bin-boundary float slop).
template<int D>
__device__ __forceinline__ float4 interp_one(
    const float4* __restrict__ lds, const float4* __restrict__ tab,
    float x, float y, float z, float scale, int res, int off,
    int Bx, int By, int Bz)
{
    float hx = x * scale + 0.5f, hy = y * scale + 0.5f, hz = z * scale + 0.5f;
    float fx = floorf(hx), fy = floorf(hy), fz = floorf(hz);
    float wx = hx - fx, wy = hy - fy, wz = hz - fz;
    float ox = 1.0f - wx, oy = 1.0f - wy, oz = 1.0f - wz;
    int gx = (int)fx, gy = (int)fy, gz = (int)fz;
    int lx = gx - Bx, ly = gy - By, lz = gz - Bz;
    float4 acc = make_float4(0.f, 0.f, 0.f, 0.f);
    if ((unsigned)lx <= (unsigned)(D - 2) &&
        (unsigned)ly <= (unsigned)(D - 2) &&
        (unsigned)lz <= (unsigned)(D - 2)) {
        int basei = (lz * D + ly) * D + lx;
#pragma unroll
        for (int c = 0; c < 8; ++c) {
            int   idx = basei + ((c & 1) ? 1 : 0) + ((c & 2) ? D : 0) + ((c & 4) ? D * D : 0);
            float w   = ((c & 1) ? wx : ox) * ((c & 2) ? wy : oy) * ((c & 4) ? wz : oz);
            float4 v  = lds[idx];
            acc.x += w * v.x; acc.y += w * v.y; acc.z += w * v.z; acc.w += w * v.w;
        }
    } else {
        int res2  = res * res;
        int basei = off + gx + gy * res + gz * res2;
#pragma unroll
        for (int c = 0; c < 8; ++c) {
            int   idx = basei + ((c & 1) ? 1 : 0) + ((c & 2) ? res : 0) + ((c & 4) ? res2 : 0);
            float w   = ((c & 1) ? wx : ox) * ((c & 2) ? wy : oy) * ((c & 4) ? wz : oz);
            float4 v  = tab[idx];
            acc.x += w * v.x; acc.y += w * v.y; acc.z += w * v.z; acc.w += w * v.w;
        }
    }
    return acc;
}

__global__ __launch_bounds__(ENC_THREADS) void encode_cap_lds_kernel(
    const float4* __restrict__ sorted,   // NBINS*CAP slots, bin b at [b*CAP, ...)
    const int* __restrict__ cursor,      // post-scatter: per-bin counts
    const float4* __restrict__ tab,
    float4* __restrict__ out,
    float s0, float s1, float s2, float s3,
    int r0, int r1, int r2, int r3,
    int o0, int o1, int o2, int o3)
{
    __shared__ float4 lds[LDS_TOT];

    // XCD-chunked swizzle: grid = NBINS*ENC_BPB = 4608, divisible by 8.
    int nb = (int)gridDim.x;
    int lb = (int)blockIdx.x;
    lb = (lb & 7) * (nb >> 3) + (lb >> 3);

    int b   = lb / ENC_BPB;
    int k   = lb - b * ENC_BPB;
    int cnt = cursor[b];
    if (k * ENC_THREADS >= cnt) return;   // uniform: whole block idle

    int tid = threadIdx.x;

    // Prefetch this thread's point record; latency hides under staging.
    int local = k * ENC_THREADS + tid;
    int j = b * CAP + local;
    vfloat4 rv = __builtin_nontemporal_load((const vfloat4*)&sorted[j]);

    // Level-0 prefetch: issue all 8 global gathers BEFORE the barrier so
    // they complete under the barrier's vmcnt drain. Coordinates clamped
    // to [0, r0-2] -- identity for valid points (hx <= 28.4 < r0-1),
    // keeps garbage/NaN records (local >= cnt lanes) in-bounds.
    float hx0 = rv.x * s0 + 0.5f, hy0 = rv.y * s0 + 0.5f, hz0 = rv.z * s0 + 0.5f;
    float fx0 = floorf(hx0), fy0 = floorf(hy0), fz0 = floorf(hz0);
    float wx0 = hx0 - fx0, wy0 = hy0 - fy0, wz0 = hz0 - fz0;
    int gx0 = (int)fx0; gx0 = gx0 < 0 ? 0 : (gx0 > r0 - 2 ? r0 - 2 : gx0);
    int gy0 = (int)fy0; gy0 = gy0 < 0 ? 0 : (gy0 > r0 - 2 ? r0 - 2 : gy0);
    int gz0 = (int)fz0; gz0 = gz0 < 0 ? 0 : (gz0 > r0 - 2 ? r0 - 2 : gz0);
    int res20 = r0 * r0;
    int base0 = o0 + gx0 + gy0 * r0 + gz0 * res20;
    float4 L0[8];
#pragma unroll
    for (int c = 0; c < 8; ++c)
        L0[c] = tab[base0 + ((c & 1) ? 1 : 0) + ((c & 2) ? r0 : 0) + ((c & 4) ? res20 : 0)];

    int bx = b & 7, by = (b >> 3) & 7, bz = b >> 6;
    float lox = bx * 0.1125f, loy = by * 0.1125f, loz = bz * 0.1125f;

    int B1x = (int)floorf(lox * s1 + 0.5f), B1y = (int)floorf(loy * s1 + 0.5f), B1z = (int)floorf(loz * s1 + 0.5f);
    int B2x = (int)floorf(lox * s2 + 0.5f), B2y = (int)floorf(loy * s2 + 0.5f), B2z = (int)floorf(loz * s2 + 0.5f);
    int B3x = (int)floorf(lox * s3 + 0.5f), B3y = (int)floorf(loy * s3 + 0.5f), B3z = (int)floorf(loz * s3 + 0.5f);

    stage_win<D1>(lds + A1, tab, o1, r1, B1x, B1y, B1z, tid);
    stage_win<D2>(lds + A2, tab, o2, r2, B2x, B2y, B2z, tid);
    stage_win<D3>(lds + A3, tab, o3, r3, B3x, B3y, B3z, tid);
    __syncthreads();

    if (local >= cnt) return;

    float x = rv.x, y = rv.y, z = rv.z;
    int p = __float_as_int(rv.w);
    float4* op = out + (long)p * 4;

    // Level 0 from the prefetched registers (weights from unclamped fracs).
    {
        float ox0 = 1.0f - wx0, oy0 = 1.0f - wy0, oz0 = 1.0f - wz0;
        float4 acc = make_float4(0.f, 0.f, 0.f, 0.f);
#pragma unroll
        for (int c = 0; c < 8; ++c) {
            float w = ((c & 1) ? wx0 : ox0) * ((c & 2) ? wy0 : oy0) * ((c & 4) ? wz0 : oz0);
            acc.x += w * L0[c].x; acc.y += w * L0[c].y;
            acc.z += w * L0[c].z; acc.w += w * L0[c].w;
        }
        op[0] = acc;
    }
    float4 a1 = interp_one<D1>(lds + A1, tab, x, y, z, s1, r1, o1, B1x, B1y, B1z);
    op[1] = a1;
    float4 a2 = interp_one<D2>(lds + A2, tab, x, y, z, s2, r2, o2, B2x, B2y, B2z);
    op[2] = a2;
    float4 a3 = interp_one<D3>(lds + A3, tab, x, y, z, s3, r3, o3, B3x, B3y, B3z);
    op[3] = a3;
}

// ---------------- shared interp (fallback paths) ----------------

__device__ __forceinline__ void interp_levels(
    float4 rec, const float4* __restrict__ tab, float4* __restrict__ o,
    float s0, float s1, float s2, float s3,
    int r0, int r1, int r2, int r3,
    int o0, int o1, int o2, int o3)
{
    float scales[4] = { s0, s1, s2, s3 };
    int   ress[4]   = { r0, r1, r2, r3 };
    int   offs[4]   = { o0, o1, o2, o3 };
#pragma unroll
    for (int l = 0; l < 4; ++l) {
        float scale = scales[l];
        int   res   = ress[l];
        int   off   = offs[l];
        float hx = rec.x * scale + 0.5f;
        float hy = rec.y * scale + 0.5f;
        float hz = rec.z * scale + 0.5f;
        float gx = floorf(hx), gy = floorf(hy), gz = floorf(hz);
        float wx = hx - gx,   wy = hy - gy,   wz = hz - gz;
        float ox = 1.0f - wx, oy = 1.0f - wy, oz = 1.0f - wz;
        int res2 = res * res;
        int base = off + (int)gx + (int)gy * res + (int)gz * res2;
        float4 acc = make_float4(0.f, 0.f, 0.f, 0.f);
#pragma unroll
        for (int c = 0; c < 8; ++c) {
            int   idx = base + ((c & 1) ? 1 : 0) + ((c & 2) ? res : 0) + ((c & 4) ? res2 : 0);
            float w   = ((c & 1) ? wx : ox) * ((c & 2) ? wy : oy) * ((c & 4) ? wz : oz);
            float4 v  = tab[idx];
            acc.x += w * v.x; acc.y += w * v.y; acc.z += w * v.z; acc.w += w * v.w;
        }
        o[l] = acc;
    }
}

// ---------------- exact-sort fallback path ----------------

__global__ __launch_bounds__(SCAT_THREADS) void hist_kernel(
    const float* __restrict__ pos, int n, int* __restrict__ hist)
{
    __shared__ int lh[NBINS];
    int tid = threadIdx.x;
    lh[tid] = 0;
    __syncthreads();
    long base = (long)blockIdx.x * PTS_PER_BLK;
#pragma unroll
    for (int j = 0; j < SCAT_ITERS; ++j) {
        long p = base + j * SCAT_THREADS + tid;
        if (p < n) {
            float x = pos[3 * p], y = pos[3 * p + 1], z = pos[3 * p + 2];
            atomicAdd(&lh[bin_of(x, y, z)], 1);
        }
    }
    __syncthreads();
    int c = lh[tid];
    if (c) atomicAdd(&hist[tid], c);
}

__global__ __launch_bounds__(256) void scan_kernel(
    const int* __restrict__ hist, int* __restrict__ cursor)
{
    __shared__ int partials[256];
    int t = threadIdx.x;
    int a = hist[2 * t], b = hist[2 * t + 1];
    int sum = a + b;
    partials[t] = sum;
    __syncthreads();
    for (int off = 1; off < 256; off <<= 1) {
        int v = (t >= off) ? partials[t - off] : 0;
        __syncthreads();
        partials[t] += v;
        __syncthreads();
    }
    int base = partials[t] - sum;
    cursor[2 * t]     = base;
    cursor[2 * t + 1] = base + a;
}

__global__ __launch_bounds__(256) void encode_kernel(
    const float4* __restrict__ sorted, const float4* __restrict__ tab,
    float4* __restrict__ out, int n,
    float s0, float s1, float s2, float s3,
    int r0, int r1, int r2, int r3,
    int o0, int o1, int o2, int o3)
{
    int j = blockIdx.x * blockDim.x + threadIdx.x;
    if (j >= n) return;
    vfloat4 rv = __builtin_nontemporal_load((const vfloat4*)&sorted[j]);
    float4 rec = make_float4(rv.x, rv.y, rv.z, rv.w);
    int p = __float_as_int(rec.w);
    interp_levels(rec, tab, out + (long)p * 4,
                  s0, s1, s2, s3, r0, r1, r2, r3, o0, o1, o2, o3);
}

__global__ __launch_bounds__(256) void encode_direct_kernel(
    const float* __restrict__ pos, const float4* __restrict__ tab,
    float4* __restrict__ out, int n_points,
    float s0, float s1, float s2, float s3,
    int r0, int r1, int r2, int r3,
    int o0, int o1, int o2, int o3)
{
    int t = blockIdx.x * blockDim.x + threadIdx.x;
    int p = t >> 2;
    if (p >= n_points) return;
    int l = t & 3;
    float scale = (l == 0) ? s0 : (l == 1) ? s1 : (l == 2) ? s2 : s3;
    int   res   = (l == 0) ? r0 : (l == 1) ? r1 : (l == 2) ? r2 : r3;
    int   off   = (l == 0) ? o0 : (l == 1) ? o1 : (l == 2) ? o2 : o3;
    float px = pos[3 * p], py = pos[3 * p + 1], pz = pos[3 * p + 2];
    float hx = px * scale + 0.5f, hy = py * scale + 0.5f, hz = pz * scale + 0.5f;
    float gx = floorf(hx), gy = floorf(hy), gz = floorf(hz);
    float wx = hx - gx, wy = hy - gy, wz = hz - gz;
    float ox = 1.f - wx, oy = 1.f - wy, oz = 1.f - wz;
    int res2 = res * res;
    int base = off + (int)gx + (int)gy * res + (int)gz * res2;
    float4 acc = make_float4(0.f, 0.f, 0.f, 0.f);
#pragma unroll
    for (int c = 0; c < 8; ++c) {
        int   idx = base + ((c & 1) ? 1 : 0) + ((c & 2) ? res : 0) + ((c & 4) ? res2 : 0);
        float w   = ((c & 1) ? wx : ox) * ((c & 2) ? wy : oy) * ((c & 4) ? wz : oz);
        float4 v  = tab[idx];
        acc.x += w * v.x; acc.y += w * v.y; acc.z += w * v.z; acc.w += w * v.w;
    }
    out[t] = acc;
}

extern "C" void kernel_launch(void* const* d_in, const int* in_sizes, int n_in,
                              void* d_out, int out_size, void* d_ws, size_t ws_size,
                              hipStream_t stream) {
    const float*  positions = (const float*)d_in[0];
    const float4* table     = (const float4*)d_in[1];
    float4*       out       = (float4*)d_out;
    int n = in_sizes[0] / 3;

    // Level metadata (double precision, matches Python reference)
    const double B_SCALE = 1.3195079565048218;
    const double BASE = 32.0;
    const long   MAX_PARAMS = 1L << 19;
    float scales[4]; int res[4], offs[4];
    long off = 0;
    for (int l = 0; l < 4; ++l) {
        double s = BASE * pow(B_SCALE, (double)l) - 1.0;
        scales[l] = (float)s;
        int r = (int)ceil(s) + 1;
        res[l] = r;
        offs[l] = (int)off;
        long pcount = (long)r * r * r;
        if (pcount % 8 != 0) pcount = (pcount + 7) / 8 * 8;
        if (pcount > MAX_PARAMS) pcount = MAX_PARAMS;
        off += pcount;
    }

    size_t need_cap   = (size_t)NBINS * sizeof(int) + (size_t)NBINS * CAP * 16;
    size_t need_exact = (size_t)NBINS * sizeof(int) * 2 + (size_t)n * 16;

    if (ws_size >= need_cap && n <= NBINS * (CAP - 512)) {
        // capacity-binning path: memset(cursor) -> scatter -> encode(LDS)
        int*    cursor = (int*)d_ws;                     // NBINS ints (rel counts)
        float4* sorted = (float4*)(cursor + NBINS);      // NBINS*CAP float4

        int grid_pts = (n + PTS_PER_BLK - 1) / PTS_PER_BLK;
        int grid_enc = NBINS * ENC_BPB;                  // 4608, %8==0 for swizzle

        (void)hipMemsetAsync(cursor, 0, NBINS * sizeof(int), stream);
        scatter_cap_kernel<<<grid_pts, SCAT_THREADS, 0, stream>>>(
            positions, n, cursor, sorted, CAP);
        encode_cap_lds_kernel<<<grid_enc, ENC_THREADS, 0, stream>>>(
            sorted, cursor, table, out,
            scales[0], scales[1], scales[2], scales[3],
            res[0], res[1], res[2], res[3],
            offs[0], offs[1], offs[2], offs[3]);
    } else if (ws_size >= need_exact) {
        int*    hist   = (int*)d_ws;
        int*    cursor = hist + NBINS;
        float4* sorted = (float4*)(cursor + NBINS);

        int grid_pts = (n + PTS_PER_BLK - 1) / PTS_PER_BLK;
        int grid_enc = (n + 255) / 256;

        (void)hipMemsetAsync(hist, 0, NBINS * sizeof(int), stream);
        hist_kernel<<<grid_pts, SCAT_THREADS, 0, stream>>>(positions, n, hist);
        scan_kernel<<<1, 256, 0, stream>>>(hist, cursor);
        scatter_cap_kernel<<<grid_pts, SCAT_THREADS, 0, stream>>>(
            positions, n, cursor, sorted, 0);
        encode_kernel<<<grid_enc, 256, 0, stream>>>(
            sorted, table, out, n,
            scales[0], scales[1], scales[2], scales[3],
            res[0], res[1], res[2], res[3],
            offs[0], offs[1], offs[2], offs[3]);
    } else {
        long n_threads = 4L * n;
        long grid = (n_threads + 255) / 256;
        encode_direct_kernel<<<dim3((unsigned)grid), dim3(256), 0, stream>>>(
            positions, table, out, n,
            scales[0], scales[1], scales[2], scales[3],
            res[0], res[1], res[2], res[3],
            offs[0], offs[1], offs[2], offs[3]);
    }
}

// Round 6
// 228.599 us; speedup vs baseline: 1.1064x; 1.1064x over previous
//
#include <hip/hip_runtime.h>
#include <math.h>

// HashEncoder, round 11.
// Capacity-binning counting sort (512 spatial bins, fixed CAP slots/bin):
//   memset(cursor) -> scatter_cap (r9, LDS-reordered) -> encode_bin.
// Round-11 changes (post-mortem of r10: both r10 changes regressed; r9 is
// the base):
//   * scatter: exact r9 version (4096 pts/block, ladder scan, LDS reorder).
//   * encode: ONE 1024-thread block per bin (grid=512 -> 2 blocks/CU =
//     32 waves/CU, no dispatch tail). All FOUR level windows staged once
//     (41.9 KB incl. L0), one barrier, then a barrier-free per-thread loop
//     over ~4.5 points with software-pipelined record prefetch. Kills the
//     9x redundant staging + 9x barriers of the 9-blocks-per-bin shape and
//     moves L0's 8 global gathers/point into LDS.
// Fallbacks: exact-sort pipeline, then direct kernel, if ws_size too small.

#define NBINS        512            // 8^3 spatial bins
#define BIN_SCALE    (8.0f / 0.9f)
#define SCAT_THREADS 512
#define PTS_PER_BLK  4096           // points per scatter block (512 thr x 8)
#define SCAT_ITERS   (PTS_PER_BLK / SCAT_THREADS)
#define CAP          4608           // slots per bin = mean 4096 + 8 sigma

#define ENC_THREADS  1024           // one block per bin

// Per-level LDS window dims: D = ceil(0.1125*scale) + 2
#define D0 6
#define D1 7
#define D2 9
#define D3 11
#define A0 0
#define A1 (A0 + D0*D0*D0)          // 216
#define A2 (A1 + D1*D1*D1)          // 559
#define A3 (A2 + D2*D2*D2)          // 1288
#define LDS_TOT (A3 + D3*D3*D3)     // 2619 float4 = 41904 B

typedef float vfloat4 __attribute__((ext_vector_type(4)));

__device__ __forceinline__ int bin_of(float x, float y, float z) {
    int bx = (int)(x * BIN_SCALE); bx = bx < 0 ? 0 : (bx > 7 ? 7 : bx);
    int by = (int)(y * BIN_SCALE); by = by < 0 ? 0 : (by > 7 ? 7 : by);
    int bz = (int)(z * BIN_SCALE); bz = bz < 0 ? 0 : (bz > 7 ? 7 : bz);
    return bx | (by << 3) | (bz << 6);
}

// ---------------- capacity-binning path ----------------

// cursor holds RELATIVE per-bin counts when bin_stride=CAP (cap path,
// cursor pre-zeroed), or ABSOLUTE scan offsets when bin_stride=0 (fallback).
// Records are bin-sorted in LDS first so global writes are contiguous
// per-bin runs instead of random 16 B scatter.  (r9-proven version.)
__global__ __launch_bounds__(SCAT_THREADS) void scatter_cap_kernel(
    const float* __restrict__ pos, int n, int* __restrict__ cursor,
    float4* __restrict__ sorted, int bin_stride)
{
    __shared__ float4         lds_rec[PTS_PER_BLK];   // 64 KB
    __shared__ unsigned short lds_bin[PTS_PER_BLK];   // 8 KB
    __shared__ int lds_hist[NBINS];                   // 2 KB
    __shared__ int lds_lbase[NBINS];                  // 2 KB (scan buffer)
    __shared__ int lds_gbase[NBINS];                  // 2 KB
    // total ~78 KB -> 2 blocks/CU (16 waves/CU)

    int tid = threadIdx.x;
    long base = (long)blockIdx.x * PTS_PER_BLK;
    lds_hist[tid] = 0;
    __syncthreads();

    // Phase 1: bin + per-block rank (LDS atomics), positions kept in regs.
    float px[SCAT_ITERS], py[SCAT_ITERS], pz[SCAT_ITERS];
    int br[SCAT_ITERS];   // packed (rank<<9)|bin, or -1
#pragma unroll
    for (int j = 0; j < SCAT_ITERS; ++j) {
        long p = base + j * SCAT_THREADS + tid;
        int packed = -1;
        if (p < n) {
            float x = pos[3 * p], y = pos[3 * p + 1], z = pos[3 * p + 2];
            px[j] = x; py[j] = y; pz[j] = z;
            int b = bin_of(x, y, z);
            int r = atomicAdd(&lds_hist[b], 1);
            packed = (r << 9) | b;
        }
        br[j] = packed;
    }
    __syncthreads();

    // Phase 2: block-wide exclusive scan of the 512-bin histogram
    // (one thread per bin), plus global base via one atomic per bin.
    int cntb = lds_hist[tid];
    lds_lbase[tid] = cntb;
    __syncthreads();
    for (int off = 1; off < NBINS; off <<= 1) {
        int v = (tid >= off) ? lds_lbase[tid - off] : 0;
        __syncthreads();
        lds_lbase[tid] += v;
        __syncthreads();
    }
    int excl = lds_lbase[tid] - cntb;          // own slot: safe pre-barrier
    if (cntb) lds_gbase[tid] = atomicAdd(&cursor[tid], cntb);
    lds_lbase[tid] = excl;
    __syncthreads();

    // Phase 3: place records bin-sorted in LDS.
#pragma unroll
    for (int j = 0; j < SCAT_ITERS; ++j) {
        if (br[j] < 0) continue;
        int b = br[j] & (NBINS - 1);
        int r = br[j] >> 9;
        int s = lds_lbase[b] + r;
        long p = base + j * SCAT_THREADS + tid;
        lds_rec[s] = make_float4(px[j], py[j], pz[j], __int_as_float((int)p));
        lds_bin[s] = (unsigned short)b;
    }
    __syncthreads();

    // Phase 4: stream LDS linearly -> contiguous per-bin runs to global.
    long rem = (long)n - base;
    int tot = rem >= PTS_PER_BLK ? PTS_PER_BLK : (rem > 0 ? (int)rem : 0);
    for (int s = tid; s < tot; s += SCAT_THREADS) {
        float4 rec = lds_rec[s];
        int b = lds_bin[s];
        int off_in_bin = s - lds_lbase[b];
        long slot = (long)b * bin_stride + lds_gbase[b] + off_in_bin;
        sorted[slot] = rec;
    }
}

// Stage one level's table window into LDS (coalesced along x).
template<int D>
__device__ __forceinline__ void stage_win(
    float4* __restrict__ dst, const float4* __restrict__ tab,
    int off, int res, int Bx, int By, int Bz, int tid)
{
    const int DD = D * D, DDD = D * D * D;
    for (int e = tid; e < DDD; e += ENC_THREADS) {
        int iz  = e / DD;
        int rem = e - iz * DD;
        int iy  = rem / D;
        int ix  = rem - iy * D;
        int gx = Bx + ix; gx = gx < 0 ? 0 : (gx > res - 1 ? res - 1 : gx);
        int gy = By + iy; gy = gy < 0 ? 0 : (gy > res - 1 ? res - 1 : gy);
        int gz = Bz + iz; gz = gz < 0 ? 0 : (gz > res - 1 ? res - 1 : gz);
        dst[e] = tab[off + gx + gy * res + gz * res * res];
    }
}

// Trilinear interp for one level, from LDS window when in range,
// exact global fallback otherwise (rare bin-boundary float slop).
template<int D>
__device__ __forceinline__ float4 interp_one(
    const float4* __restrict__ lds, const float4* __restrict__ tab,
    float x, float y, float z, float scale, int res, int off,
    int Bx, int By, int Bz)
{
    float hx = x * scale + 0.5f, hy = y * scale + 0.5f, hz = z * scale + 0.5f;
    float fx = floorf(hx), fy = floorf(hy), fz = floorf(hz);
    float wx = hx - fx, wy = hy - fy, wz = hz - fz;
    float ox = 1.0f - wx, oy = 1.0f - wy, oz = 1.0f - wz;
    int gx = (int)fx, gy = (int)fy, gz = (int)fz;
    int lx = gx - Bx, ly = gy - By, lz = gz - Bz;
    float4 acc = make_float4(0.f, 0.f, 0.f, 0.f);
    if ((unsigned)lx <= (unsigned)(D - 2) &&
        (unsigned)ly <= (unsigned)(D - 2) &&
        (unsigned)lz <= (unsigned)(D - 2)) {
        int basei = (lz * D + ly) * D + lx;
#pragma unroll
        for (int c = 0; c < 8; ++c) {
            int   idx = basei + ((c & 1) ? 1 : 0) + ((c & 2) ? D : 0) + ((c & 4) ? D * D : 0);
            float w   = ((c & 1) ? wx : ox) * ((c & 2) ? wy : oy) * ((c & 4) ? wz : oz);
            float4 v  = lds[idx];
            acc.x += w * v.x; acc.y += w * v.y; acc.z += w * v.z; acc.w += w * v.w;
        }
    } else {
        int res2  = res * res;
        int basei = off + gx + gy * res + gz * res2;
#pragma unroll
        for (int c = 0; c < 8; ++c) {
            int   idx = basei + ((c & 1) ? 1 : 0) + ((c & 2) ? res : 0) + ((c & 4) ? res2 : 0);
            float w   = ((c & 1) ? wx : ox) * ((c & 2) ? wy : oy) * ((c & 4) ? wz : oz);
            float4 v  = tab[idx];
            acc.x += w * v.x; acc.y += w * v.y; acc.z += w * v.z; acc.w += w * v.w;
        }
    }
    return acc;
}

// One block per bin: stage all 4 windows once, then barrier-free point loop.
__global__ __launch_bounds__(ENC_THREADS) void encode_bin_kernel(
    const float4* __restrict__ sorted,   // NBINS*CAP slots, bin b at [b*CAP, ...)
    const int* __restrict__ cursor,      // post-scatter: per-bin counts
    const float4* __restrict__ tab,
    float4* __restrict__ out,
    float s0, float s1, float s2, float s3,
    int r0, int r1, int r2, int r3,
    int o0, int o1, int o2, int o3)
{
    __shared__ float4 lds[LDS_TOT];

    // XCD-chunked swizzle: grid = NBINS = 512, divisible by 8.
    int nb = (int)gridDim.x;
    int b  = (int)blockIdx.x;
    b = (b & 7) * (nb >> 3) + (b >> 3);

    int cnt = cursor[b];
    int tid = threadIdx.x;

    int bx = b & 7, by = (b >> 3) & 7, bz = b >> 6;
    float lox = bx * 0.1125f, loy = by * 0.1125f, loz = bz * 0.1125f;

    int B0x = (int)floorf(lox * s0 + 0.5f), B0y = (int)floorf(loy * s0 + 0.5f), B0z = (int)floorf(loz * s0 + 0.5f);
    int B1x = (int)floorf(lox * s1 + 0.5f), B1y = (int)floorf(loy * s1 + 0.5f), B1z = (int)floorf(loz * s1 + 0.5f);
    int B2x = (int)floorf(lox * s2 + 0.5f), B2y = (int)floorf(loy * s2 + 0.5f), B2z = (int)floorf(loz * s2 + 0.5f);
    int B3x = (int)floorf(lox * s3 + 0.5f), B3y = (int)floorf(loy * s3 + 0.5f), B3z = (int)floorf(loz * s3 + 0.5f);

    stage_win<D0>(lds + A0, tab, o0, r0, B0x, B0y, B0z, tid);
    stage_win<D1>(lds + A1, tab, o1, r1, B1x, B1y, B1z, tid);
    stage_win<D2>(lds + A2, tab, o2, r2, B2x, B2y, B2z, tid);
    stage_win<D3>(lds + A3, tab, o3, r3, B3x, B3y, B3z, tid);
    __syncthreads();

    if (cnt == 0) return;

    int iters = (cnt + ENC_THREADS - 1) / ENC_THREADS;
    const float4* sbin = sorted + (long)b * CAP;
    int jmax = CAP - 1;

    int local = tid;
    vfloat4 rv = __builtin_nontemporal_load(
        (const vfloat4*)&sbin[local <= jmax ? local : jmax]);

    for (int it = 0; it < iters; ++it) {
        int nloc = local + ENC_THREADS;
        vfloat4 nx = rv;
        if (it + 1 < iters)
            nx = __builtin_nontemporal_load(
                (const vfloat4*)&sbin[nloc <= jmax ? nloc : jmax]);
        if (local < cnt) {
            float x = rv.x, y = rv.y, z = rv.z;
            int p = __float_as_int(rv.w);
            float4* op = out + (long)p * 4;
            // All four levels from LDS; stores deferred so the compiler can
            // interleave the 32 independent LDS reads.
            float4 a0 = interp_one<D0>(lds + A0, tab, x, y, z, s0, r0, o0, B0x, B0y, B0z);
            float4 a1 = interp_one<D1>(lds + A1, tab, x, y, z, s1, r1, o1, B1x, B1y, B1z);
            float4 a2 = interp_one<D2>(lds + A2, tab, x, y, z, s2, r2, o2, B2x, B2y, B2z);
            float4 a3 = interp_one<D3>(lds + A3, tab, x, y, z, s3, r3, o3, B3x, B3y, B3z);
            op[0] = a0; op[1] = a1; op[2] = a2; op[3] = a3;
        }
        rv = nx;
        local = nloc;
    }
}

// ---------------- shared interp (fallback paths) ----------------

__device__ __forceinline__ void interp_levels(
    float4 rec, const float4* __restrict__ tab, float4* __restrict__ o,
    float s0, float s1, float s2, float s3,
    int r0, int r1, int r2, int r3,
    int o0, int o1, int o2, int o3)
{
    float scales[4] = { s0, s1, s2, s3 };
    int   ress[4]   = { r0, r1, r2, r3 };
    int   offs[4]   = { o0, o1, o2, o3 };
#pragma unroll
    for (int l = 0; l < 4; ++l) {
        float scale = scales[l];
        int   res   = ress[l];
        int   off   = offs[l];
        float hx = rec.x * scale + 0.5f;
        float hy = rec.y * scale + 0.5f;
        float hz = rec.z * scale + 0.5f;
        float gx = floorf(hx), gy = floorf(hy), gz = floorf(hz);
        float wx = hx - gx,   wy = hy - gy,   wz = hz - gz;
        float ox = 1.0f - wx, oy = 1.0f - wy, oz = 1.0f - wz;
        int res2 = res * res;
        int base = off + (int)gx + (int)gy * res + (int)gz * res2;
        float4 acc = make_float4(0.f, 0.f, 0.f, 0.f);
#pragma unroll
        for (int c = 0; c < 8; ++c) {
            int   idx = base + ((c & 1) ? 1 : 0) + ((c & 2) ? res : 0) + ((c & 4) ? res2 : 0);
            float w   = ((c & 1) ? wx : ox) * ((c & 2) ? wy : oy) * ((c & 4) ? wz : oz);
            float4 v  = tab[idx];
            acc.x += w * v.x; acc.y += w * v.y; acc.z += w * v.z; acc.w += w * v.w;
        }
        o[l] = acc;
    }
}

// ---------------- exact-sort fallback path ----------------

__global__ __launch_bounds__(SCAT_THREADS) void hist_kernel(
    const float* __restrict__ pos, int n, int* __restrict__ hist)
{
    __shared__ int lh[NBINS];
    int tid = threadIdx.x;
    lh[tid] = 0;
    __syncthreads();
    long base = (long)blockIdx.x * PTS_PER_BLK;
#pragma unroll
    for (int j = 0; j < SCAT_ITERS; ++j) {
        long p = base + j * SCAT_THREADS + tid;
        if (p < n) {
            float x = pos[3 * p], y = pos[3 * p + 1], z = pos[3 * p + 2];
            atomicAdd(&lh[bin_of(x, y, z)], 1);
        }
    }
    __syncthreads();
    int c = lh[tid];
    if (c) atomicAdd(&hist[tid], c);
}

__global__ __launch_bounds__(256) void scan_kernel(
    const int* __restrict__ hist, int* __restrict__ cursor)
{
    __shared__ int partials[256];
    int t = threadIdx.x;
    int a = hist[2 * t], b = hist[2 * t + 1];
    int sum = a + b;
    partials[t] = sum;
    __syncthreads();
    for (int off = 1; off < 256; off <<= 1) {
        int v = (t >= off) ? partials[t - off] : 0;
        __syncthreads();
        partials[t] += v;
        __syncthreads();
    }
    int base = partials[t] - sum;
    cursor[2 * t]     = base;
    cursor[2 * t + 1] = base + a;
}

__global__ __launch_bounds__(256) void encode_kernel(
    const float4* __restrict__ sorted, const float4* __restrict__ tab,
    float4* __restrict__ out, int n,
    float s0, float s1, float s2, float s3,
    int r0, int r1, int r2, int r3,
    int o0, int o1, int o2, int o3)
{
    int j = blockIdx.x * blockDim.x + threadIdx.x;
    if (j >= n) return;
    vfloat4 rv = __builtin_nontemporal_load((const vfloat4*)&sorted[j]);
    float4 rec = make_float4(rv.x, rv.y, rv.z, rv.w);
    int p = __float_as_int(rec.w);
    interp_levels(rec, tab, out + (long)p * 4,
                  s0, s1, s2, s3, r0, r1, r2, r3, o0, o1, o2, o3);
}

__global__ __launch_bounds__(256) void encode_direct_kernel(
    const float* __restrict__ pos, const float4* __restrict__ tab,
    float4* __restrict__ out, int n_points,
    float s0, float s1, float s2, float s3,
    int r0, int r1, int r2, int r3,
    int o0, int o1, int o2, int o3)
{
    int t = blockIdx.x * blockDim.x + threadIdx.x;
    int p = t >> 2;
    if (p >= n_points) return;
    int l = t & 3;
    float scale = (l == 0) ? s0 : (l == 1) ? s1 : (l == 2) ? s2 : s3;
    int   res   = (l == 0) ? r0 : (l == 1) ? r1 : (l == 2) ? r2 : r3;
    int   off   = (l == 0) ? o0 : (l == 1) ? o1 : (l == 2) ? o2 : o3;
    float px = pos[3 * p], py = pos[3 * p + 1], pz = pos[3 * p + 2];
    float hx = px * scale + 0.5f, hy = py * scale + 0.5f, hz = pz * scale + 0.5f;
    float gx = floorf(hx), gy = floorf(hy), gz = floorf(hz);
    float wx = hx - gx, wy = hy - gy, wz = hz - gz;
    float ox = 1.f - wx, oy = 1.f - wy, oz = 1.f - wz;
    int res2 = res * res;
    int base = off + (int)gx + (int)gy * res + (int)gz * res2;
    float4 acc = make_float4(0.f, 0.f, 0.f, 0.f);
#pragma unroll
    for (int c = 0; c < 8; ++c) {
        int   idx = base + ((c & 1) ? 1 : 0) + ((c & 2) ? res : 0) + ((c & 4) ? res2 : 0);
        float w   = ((c & 1) ? wx : ox) * ((c & 2) ? wy : oy) * ((c & 4) ? wz : oz);
        float4 v  = tab[idx];
        acc.x += w * v.x; acc.y += w * v.y; acc.z += w * v.z; acc.w += w * v.w;
    }
    out[t] = acc;
}

extern "C" void kernel_launch(void* const* d_in, const int* in_sizes, int n_in,
                              void* d_out, int out_size, void* d_ws, size_t ws_size,
                              hipStream_t stream) {
    const float*  positions = (const float*)d_in[0];
    const float4* table     = (const float4*)d_in[1];
    float4*       out       = (float4*)d_out;
    int n = in_sizes[0] / 3;

    // Level metadata (double precision, matches Python reference)
    const double B_SCALE = 1.3195079565048218;
    const double BASE = 32.0;
    const long   MAX_PARAMS = 1L << 19;
    float scales[4]; int res[4], offs[4];
    long off = 0;
    for (int l = 0; l < 4; ++l) {
        double s = BASE * pow(B_SCALE, (double)l) - 1.0;
        scales[l] = (float)s;
        int r = (int)ceil(s) + 1;
        res[l] = r;
        offs[l] = (int)off;
        long pcount = (long)r * r * r;
        if (pcount % 8 != 0) pcount = (pcount + 7) / 8 * 8;
        if (pcount > MAX_PARAMS) pcount = MAX_PARAMS;
        off += pcount;
    }

    size_t need_cap   = (size_t)NBINS * sizeof(int) + (size_t)NBINS * CAP * 16;
    size_t need_exact = (size_t)NBINS * sizeof(int) * 2 + (size_t)n * 16;

    if (ws_size >= need_cap && n <= NBINS * (CAP - 512)) {
        // capacity-binning path: memset(cursor) -> scatter -> encode(bin)
        int*    cursor = (int*)d_ws;                     // NBINS ints (rel counts)
        float4* sorted = (float4*)(cursor + NBINS);      // NBINS*CAP float4

        int grid_pts = (n + PTS_PER_BLK - 1) / PTS_PER_BLK;

        (void)hipMemsetAsync(cursor, 0, NBINS * sizeof(int), stream);
        scatter_cap_kernel<<<grid_pts, SCAT_THREADS, 0, stream>>>(
            positions, n, cursor, sorted, CAP);
        encode_bin_kernel<<<NBINS, ENC_THREADS, 0, stream>>>(
            sorted, cursor, table, out,
            scales[0], scales[1], scales[2], scales[3],
            res[0], res[1], res[2], res[3],
            offs[0], offs[1], offs[2], offs[3]);
    } else if (ws_size >= need_exact) {
        int*    hist   = (int*)d_ws;
        int*    cursor = hist + NBINS;
        float4* sorted = (float4*)(cursor + NBINS);

        int grid_pts = (n + PTS_PER_BLK - 1) / PTS_PER_BLK;
        int grid_enc = (n + 255) / 256;

        (void)hipMemsetAsync(hist, 0, NBINS * sizeof(int), stream);
        hist_kernel<<<grid_pts, SCAT_THREADS, 0, stream>>>(positions, n, hist);
        scan_kernel<<<1, 256, 0, stream>>>(hist, cursor);
        scatter_cap_kernel<<<grid_pts, SCAT_THREADS, 0, stream>>>(
            positions, n, cursor, sorted, 0);
        encode_kernel<<<grid_enc, 256, 0, stream>>>(
            sorted, table, out, n,
            scales[0], scales[1], scales[2], scales[3],
            res[0], res[1], res[2], res[3],
            offs[0], offs[1], offs[2], offs[3]);
    } else {
        long n_threads = 4L * n;
        long grid = (n_threads + 255) / 256;
        encode_direct_kernel<<<dim3((unsigned)grid), dim3(256), 0, stream>>>(
            positions, table, out, n,
            scales[0], scales[1], scales[2], scales[3],
            res[0], res[1], res[2], res[3],
            offs[0], offs[1], offs[2], offs[3]);
    }
}